// Round 10
// baseline (289.179 us; speedup 1.0000x reference)
//
#include <hip/hip_runtime.h>
#include <hip/hip_bf16.h>
#include <stdint.h>

#define TOKENS 8192
#define NF 4096   // out features
#define KF 4096   // in features
#define RANK 16

typedef __attribute__((ext_vector_type(8))) short bf16x8;
typedef __attribute__((ext_vector_type(4))) float f32x4;
typedef __attribute__((ext_vector_type(8))) unsigned short u16x8;

static __device__ __forceinline__ unsigned short f2b(float f) {
    union { float f; uint32_t u; } v; v.f = f;
    uint32_t u = v.u;
    uint32_t r = (u + 0x7fffu + ((u >> 16) & 1u)) >> 16;   // RNE
    return (unsigned short)r;
}

// Wt[n][k] = bf16( W[k][n] + sum_r U[k][r]*s[r]*Vt[r][n] )  (transposed, K-contiguous)
__global__ __launch_bounds__(256) void prep_w_kernel(
    const float* __restrict__ W, const float* __restrict__ U,
    const float* __restrict__ s, const float* __restrict__ Vt,
    unsigned short* __restrict__ Wt)
{
    __shared__ float Us[64][16];
    __shared__ float Vs[16][64];
    __shared__ float tile[64][65];   // [k][n]
    const int kb = blockIdx.x, nb = blockIdx.y;
    const int t = threadIdx.x;
    for (int idx = t; idx < 64 * 16; idx += 256) {
        int kl = idx >> 4, r = idx & 15;
        Us[kl][r] = U[(size_t)(kb * 64 + kl) * RANK + r];
    }
    for (int idx = t; idx < 16 * 64; idx += 256) {
        int r = idx >> 6, nl = idx & 63;
        Vs[r][nl] = Vt[(size_t)r * NF + nb * 64 + nl] * s[r];
    }
    __syncthreads();
    const int nl = t & 63, kl0 = t >> 6;
    for (int i = 0; i < 16; ++i) {
        int kl = kl0 + i * 4;
        float v = __builtin_nontemporal_load(&W[(size_t)(kb * 64 + kl) * NF + nb * 64 + nl]);
        #pragma unroll
        for (int r = 0; r < RANK; ++r) v += Us[kl][r] * Vs[r][nl];
        tile[kl][nl] = v;
    }
    __syncthreads();
    // vectorized write: 512 items (n, kg); 16B/lane stores, 128B segments
    #pragma unroll
    for (int j = 0; j < 2; ++j) {
        int idx = t + j * 256;
        int kg = idx & 7, n = idx >> 3;
        u16x8 o;
        #pragma unroll
        for (int e = 0; e < 8; ++e) o[e] = f2b(tile[kg * 8 + e][n]);
        *(u16x8*)&Wt[(size_t)(nb * 64 + n) * KF + kb * 64 + kg * 8] = o;
    }
}

__global__ __launch_bounds__(256) void prep_x_kernel(
    const float* __restrict__ x, unsigned short* __restrict__ xb)
{
    size_t base = ((size_t)blockIdx.x * 256 + threadIdx.x) * 8;
    f32x4 a = __builtin_nontemporal_load((const f32x4*)(x + base));
    f32x4 b = __builtin_nontemporal_load((const f32x4*)(x + base + 4));
    u16x8 o;
    o[0] = f2b(a[0]); o[1] = f2b(a[1]); o[2] = f2b(a[2]); o[3] = f2b(a[3]);
    o[4] = f2b(b[0]); o[5] = f2b(b[1]); o[6] = f2b(b[2]); o[7] = f2b(b[3]);
    *(u16x8*)(xb + base) = o;
}

// ---------------------------------------------------------------------------
// 256x256 GEMM, 4 merged phases/iter (2 K-tiles), single barrier per phase.
// A = xb [TOKENS][KF]; Bt = Wt [NF][KF]. 8 waves (2M x 4N).
// LDS 128 KiB = {A,B} x {dbuf} x {half} x [128][64] bf16, XOR swizzle
// (byte ^= (row&7)<<4) via pre-swizzled global source, linear gload_lds dest.
// Phase = {stage 1 full region (2x stage = 4 gload_lds); [VM4]; barrier;
//          mem-fence; setprio1; [LDB next-B in ckpt shadow]; LDA8 in-phase
//          (compiler interleaves lgkmcnt with MFMA); 32 MFMA; setprio0}.
// Stage map (same ledger as rounds 2..8, 2 old-phases merged):
//   NP1: A-d1 (kt1)             compute d0 qh0 (acc[0..3],  bfrP, A-d0 kt2i)
//   NP2: B-d0 (kt2) + VM4       compute d0 qh1; shadow: bfrQ <- B-d1(kt1)
//   NP3: A-d0 (kt2)             compute d1 qh0 (bfrQ, A-d1 kt1)
//   NP4: B-d1 (kt3) + VM4       compute d1 qh1; shadow: bfrP <- B-d0(kt2)
// vmcnt ledger (4 instr/phase): enter NP1 with 4 (B-d1 kt1); NP2 VM4
// retires B-d1(kt1)+A-d1(kt1) -> its shadow reads exactly those ✓; NP4 VM4
// retires B-d0(kt2)+A-d0(kt2) -> shadow reads those ✓.  All frag reads are
// post-barrier reads of VM4-drained regions (stricter than r8's prefetch).
// WAR: every region's reads are issued >=1 barrier before the overwriting
// stage-issue (+~300cy DMA landing) — same margins as proven rounds.
// ---------------------------------------------------------------------------

#define VM4  asm volatile("s_waitcnt vmcnt(4)" ::: "memory")

#define MFMA(a, b, c) __builtin_amdgcn_mfma_f32_16x16x32_bf16(a, b, c, 0, 0, 0)

// 8 A-frag reads for half qh of d-group dn: mf = 4*qh + j, kk = 0..1
#define LDA8(dn, qh, afr) do {                                                  \
    _Pragma("unroll")                                                           \
    for (int j = 0; j < 4; ++j) {                                               \
        afr[2*j]   = ldA(dn, 4*(qh) + j, 0);                                    \
        afr[2*j+1] = ldA(dn, 4*(qh) + j, 1);                                    \
    } } while (0)

#define LDB_ALL(d, bfr) do {                                                    \
    _Pragma("unroll")                                                           \
    for (int nf = 0; nf < 4; ++nf) {                                            \
        bfr[nf][0] = ldB(d, nf, 0);                                             \
        bfr[nf][1] = ldB(d, nf, 1);                                             \
    } } while (0)

// 32 MFMA: acc[4*qh + j][nf] over j=0..3, nf=0..3, kk=0..1
#define MFMA32(qh, bfr, afr) do {                                               \
    _Pragma("unroll")                                                           \
    for (int j = 0; j < 4; ++j)                                                 \
        _Pragma("unroll")                                                       \
        for (int nf = 0; nf < 4; ++nf) {                                        \
            acc[4*(qh)+j][nf] = MFMA(afr[2*j],   bfr[nf][0], acc[4*(qh)+j][nf]);\
            acc[4*(qh)+j][nf] = MFMA(afr[2*j+1], bfr[nf][1], acc[4*(qh)+j][nf]);\
        } } while (0)

// regular merged phase
#define PHASE4(dc, qh, bfr, STAGE_EXPR) do {                                    \
    STAGE_EXPR;                                                                 \
    __builtin_amdgcn_s_barrier();                                               \
    asm volatile("" ::: "memory");                                              \
    __builtin_amdgcn_s_setprio(1);                                              \
    LDA8(dc, qh, afr);                                                          \
    MFMA32(qh, bfr, afr);                                                       \
    __builtin_amdgcn_s_setprio(0);                                              \
} while (0)

// checkpoint merged phase: + VM4 pre-barrier, + next-B preload in shadow
#define PHASE4X(dc, qh, bfr, bnxt, dnb, STAGE_EXPR) do {                        \
    STAGE_EXPR;                                                                 \
    VM4;                                                                        \
    __builtin_amdgcn_s_barrier();                                               \
    asm volatile("" ::: "memory");                                              \
    __builtin_amdgcn_s_setprio(1);                                              \
    LDB_ALL(dnb, bnxt);                                                         \
    LDA8(dc, qh, afr);                                                          \
    MFMA32(qh, bfr, afr);                                                       \
    __builtin_amdgcn_s_setprio(0);                                              \
} while (0)

__global__ __launch_bounds__(512, 2) void gemm_kernel(
    const unsigned short* __restrict__ A,
    const unsigned short* __restrict__ Bt,
    float* __restrict__ C)
{
    __shared__ __align__(16) unsigned short lds[65536];   // 128 KiB

    const int tid  = threadIdx.x;
    const int lane = tid & 63;
    const int wave = tid >> 6;
    const int wm = wave >> 2;          // 0..1
    const int wn = wave & 3;           // 0..3

    // XCD-aware swizzle: 512 blocks, 512 % 8 == 0 -> bijective
    const int bid = blockIdx.x;
    const int swz = (bid & 7) * 64 + (bid >> 3);
    const int tm = swz >> 4;           // 32 M-tiles
    const int tn = swz & 15;           // 16 N-tiles

    const int frow = lane & 15;
    const int kgrp = lane >> 4;
    const int xorv = (frow & 7) << 4;  // read-side byte XOR (bits 4-6)

    // staging: thread tid covers LDS bytes [tid*16, tid*16+16) (+8KB for h=1).
    // source col pre-swizzled with the same involution; LDS dest stays linear.
    const int st_row  = tid >> 3;                                            // 0..63
    const int st_colE = ((((tid & 7) * 16) ^ (((tid >> 3) & 7) << 4)) >> 1); // elems
    const unsigned short* aSrc = A  + (size_t)(tm * 256 + st_row) * KF + st_colE;
    const unsigned short* bSrc = Bt + (size_t)(tn * 256 + st_row) * KF + st_colE;
    const int dstE = tid * 8;

    f32x4 acc[8][4] = {};

    auto stage = [&](int isB, int d, int h, int kt) {
        const unsigned short* src =
            (isB ? bSrc : aSrc) + (size_t)((h) * 128) * KF + (kt) * 64;
        unsigned short* dst = (unsigned short*)&lds[isB * 32768 + (d * 2 + h) * 8192 + dstE];
        __builtin_amdgcn_global_load_lds(
            (const __attribute__((address_space(1))) void*)src,
            (__attribute__((address_space(3))) void*)dst, 16, 0, 0);
        __builtin_amdgcn_global_load_lds(
            (const __attribute__((address_space(1))) void*)(src + (size_t)64 * KF),
            (__attribute__((address_space(3))) void*)(dst + 4096), 16, 0, 0);
    };

    auto ldA = [&](int d, int mf, int kk) -> bf16x8 {
        int off = (d * 2 + wm) * 8192 + (mf * 16 + frow) * 64
                + ((((kk << 6) | (kgrp << 4)) ^ xorv) >> 1);
        return *(const bf16x8*)&lds[off];
    };
    auto ldB = [&](int d, int nf, int kk) -> bf16x8 {
        int off = 32768 + (d * 2 + (wn >> 1)) * 8192
                + ((wn & 1) * 64 + nf * 16 + frow) * 64
                + ((((kk << 6) | (kgrp << 4)) ^ xorv) >> 1);
        return *(const bf16x8*)&lds[off];
    };

    bf16x8 bfrP[4][2], bfrQ[4][2];
    bf16x8 afr[8];

    // ---- prologue: B-d0(K0), A-d0(K0), B-d1(K1); VM4 retires B-d0+A-d0
    // (FIFO), leaving B-d1 in flight = steady-state carry. After the barrier
    // all waves' K0 writes are visible -> preload bfrP.
    stage(1, 0, 0, 0); stage(1, 0, 1, 0);
    stage(0, 0, 0, 0); stage(0, 0, 1, 0);
    stage(1, 1, 0, 1); stage(1, 1, 1, 1);
    VM4;
    __builtin_amdgcn_s_barrier();
    asm volatile("" ::: "memory");     // keep preloads below the barrier
    LDB_ALL(0, bfrP);

    // ---- main loop: 64 K-tiles, 2 per iteration, 4 merged phases ----
    for (int i = 0; i < 32; ++i) {
        const int kt1 = 2 * i + 1;
        const int kt2 = (2 * i + 2) & 63;   // wrap on last iter (dead data, safe)
        const int kt3 = (2 * i + 3) & 63;

        PHASE4 (0, 0, bfrP, (stage(0, 1, 0, kt1), stage(0, 1, 1, kt1)));            // NP1
        PHASE4X(0, 1, bfrP, bfrQ, 1, (stage(1, 0, 0, kt2), stage(1, 0, 1, kt2)));   // NP2
        PHASE4 (1, 0, bfrQ, (stage(0, 0, 0, kt2), stage(0, 0, 1, kt2)));            // NP3
        PHASE4X(1, 1, bfrQ, bfrP, 0, (stage(1, 1, 0, kt3), stage(1, 1, 1, kt3)));   // NP4
    }

    asm volatile("s_waitcnt vmcnt(0)" ::: "memory");

    // ---- epilogue: C/D layout col=lane&15, row=(lane>>4)*4+reg ----
    const int rgrp = lane >> 4, coll = lane & 15;
    #pragma unroll
    for (int mf = 0; mf < 8; ++mf)
        #pragma unroll
        for (int nf = 0; nf < 4; ++nf) {
            size_t row0 = (size_t)(tm * 256 + wm * 128 + mf * 16 + rgrp * 4);
            size_t col  = (size_t)(tn * 256 + wn * 64 + nf * 16 + coll);
            #pragma unroll
            for (int r = 0; r < 4; ++r)
                C[(row0 + r) * NF + col] = acc[mf][nf][r];
        }
}

extern "C" void kernel_launch(void* const* d_in, const int* in_sizes, int n_in,
                              void* d_out, int out_size, void* d_ws, size_t ws_size,
                              hipStream_t stream) {
    const float* x  = (const float*)d_in[0];
    const float* W  = (const float*)d_in[1];
    const float* U  = (const float*)d_in[2];
    const float* s  = (const float*)d_in[3];
    const float* Vt = (const float*)d_in[4];
    float* out = (float*)d_out;

    unsigned short* Wt = (unsigned short*)d_ws;                  // 32 MB
    unsigned short* xb = Wt + (size_t)NF * KF;                   // 64 MB

    prep_w_kernel<<<dim3(KF / 64, NF / 64), 256, 0, stream>>>(W, U, s, Vt, Wt);
    prep_x_kernel<<<(TOKENS * KF / 8) / 256, 256, 0, stream>>>(x, xb);
    gemm_kernel<<<(TOKENS / 256) * (NF / 256), 512, 0, stream>>>(xb, Wt, out);
}

// Round 11
// 269.200 us; speedup vs baseline: 1.0742x; 1.0742x over previous
//
#include <hip/hip_runtime.h>
#include <hip/hip_bf16.h>
#include <stdint.h>

#define TOKENS 8192
#define NF 4096   // out features
#define KF 4096   // in features
#define RANK 16

typedef __attribute__((ext_vector_type(8))) short bf16x8;
typedef __attribute__((ext_vector_type(4))) float f32x4;
typedef __attribute__((ext_vector_type(8))) unsigned short u16x8;

static __device__ __forceinline__ unsigned short f2b(float f) {
    union { float f; uint32_t u; } v; v.f = f;
    uint32_t u = v.u;
    uint32_t r = (u + 0x7fffu + ((u >> 16) & 1u)) >> 16;   // RNE
    return (unsigned short)r;
}

// Wt[n][k] = bf16( W[k][n] + sum_r U[k][r]*s[r]*Vt[r][n] )  (transposed, K-contiguous)
// Vectorized: W/U/Vt loaded as f32x4 (16B/lane); LDS tile stride 65 kept
// (conflict-free transpose read; +4 pad would be 8-way-conflicted).
__global__ __launch_bounds__(256) void prep_w_kernel(
    const float* __restrict__ W, const float* __restrict__ U,
    const float* __restrict__ s, const float* __restrict__ Vt,
    unsigned short* __restrict__ Wt)
{
    __shared__ float Us[64][16];
    __shared__ float Vs[16][64];
    __shared__ float tile[64][65];   // [k][n]
    const int kb = blockIdx.x, nb = blockIdx.y;
    const int t = threadIdx.x;
    // U block: 1024 contiguous f32 at kb*1024
    {
        f32x4 u = *(const f32x4*)&U[(size_t)kb * 1024 + t * 4];
        *(f32x4*)&((float*)Us)[t * 4] = u;
    }
    // Vt block: 16 rows x 64 cols, pre-scaled by s[r]
    {
        const int r = t >> 4, nq = t & 15;
        f32x4 v = *(const f32x4*)&Vt[(size_t)r * NF + nb * 64 + nq * 4];
        const float sc = s[r];
        v[0] *= sc; v[1] *= sc; v[2] *= sc; v[3] *= sc;
        *(f32x4*)&Vs[r][nq * 4] = v;
    }
    __syncthreads();
    // compute: 1024 f32x4 quads; thread does 4 (W nontemporal: never re-read)
    #pragma unroll
    for (int j = 0; j < 4; ++j) {
        const int idx = t + j * 256;
        const int kl = idx >> 4, qc = idx & 15;
        f32x4 v = __builtin_nontemporal_load(
            (const f32x4*)&W[(size_t)(kb * 64 + kl) * NF + nb * 64 + qc * 4]);
        #pragma unroll
        for (int r = 0; r < RANK; ++r) {
            const float u = Us[kl][r];
            v[0] += u * Vs[r][qc * 4 + 0];
            v[1] += u * Vs[r][qc * 4 + 1];
            v[2] += u * Vs[r][qc * 4 + 2];
            v[3] += u * Vs[r][qc * 4 + 3];
        }
        tile[kl][qc * 4 + 0] = v[0];   // scalar LDS writes (stride-65 rows)
        tile[kl][qc * 4 + 1] = v[1];
        tile[kl][qc * 4 + 2] = v[2];
        tile[kl][qc * 4 + 3] = v[3];
    }
    __syncthreads();
    // transposed write: 512 items (n, kg); 16B/lane stores, 128B segments
    #pragma unroll
    for (int j = 0; j < 2; ++j) {
        int idx = t + j * 256;
        int kg = idx & 7, n = idx >> 3;
        u16x8 o;
        #pragma unroll
        for (int e = 0; e < 8; ++e) o[e] = f2b(tile[kg * 8 + e][n]);
        *(u16x8*)&Wt[(size_t)(nb * 64 + n) * KF + kb * 64 + kg * 8] = o;
    }
}

__global__ __launch_bounds__(256) void prep_x_kernel(
    const float* __restrict__ x, unsigned short* __restrict__ xb)
{
    size_t base = ((size_t)blockIdx.x * 256 + threadIdx.x) * 8;
    f32x4 a = __builtin_nontemporal_load((const f32x4*)(x + base));
    f32x4 b = __builtin_nontemporal_load((const f32x4*)(x + base + 4));
    u16x8 o;
    o[0] = f2b(a[0]); o[1] = f2b(a[1]); o[2] = f2b(a[2]); o[3] = f2b(a[3]);
    o[4] = f2b(b[0]); o[5] = f2b(b[1]); o[6] = f2b(b[2]); o[7] = f2b(b[3]);
    *(u16x8*)(xb + base) = o;
}

// ---------------------------------------------------------------------------
// 256x256 8-phase GEMM, SINGLE barrier per phase + full shadow prefetch.
// (round-8-proven: 212.8 us, MfmaUtil 60.6, 0 bank conflicts — byte-identical)
// A = xb [TOKENS][KF]; Bt = Wt [NF][KF]. 8 waves (2M x 4N).
// LDS 128 KiB = {A,B} x {dbuf} x {half} x [128][64] bf16, XOR swizzle
// (byte ^= (row&7)<<4) via pre-swizzled global source, linear gload_lds dest.
// Stage map:
//   P1:A-d1 h0(kt1) P2:A-d1 h1(kt1) P3:B-d0 h0(kt2) P4:B-d0 h1(kt2)+VM4
//   P5:A-d0 h0(kt2) P6:A-d0 h1(kt2) P7:B-d1 h0(kt3) P8:B-d1 h1(kt3)+VM4
// Phase = {stage; [VM4]; s_barrier; lgkmcnt(0); setprio1; shadow-reads
// (next-phase A-frags; next-d B-frags at P4/P8); 16 MFMA; setprio0}.
// Hazard proof: see rounds 6/8 — all RAW/WAR edges barrier-ordered.
// ---------------------------------------------------------------------------

#define VM4  asm volatile("s_waitcnt vmcnt(4)" ::: "memory")

#define MFMA(a, b, c) __builtin_amdgcn_mfma_f32_16x16x32_bf16(a, b, c, 0, 0, 0)

#define LDA4(dn, qn, afr) do {                                                  \
    afr[0] = ldA(dn, 2*(qn), 0);   afr[1] = ldA(dn, 2*(qn), 1);                 \
    afr[2] = ldA(dn, 2*(qn)+1, 0); afr[3] = ldA(dn, 2*(qn)+1, 1);               \
} while (0)

#define LDB_ALL(d, bfr) do {                                                    \
    _Pragma("unroll")                                                           \
    for (int nf = 0; nf < 4; ++nf) {                                            \
        bfr[nf][0] = ldB(d, nf, 0);                                             \
        bfr[nf][1] = ldB(d, nf, 1);                                             \
    } } while (0)

#define MFMA16(q, bfr, afr) do {                                                \
    _Pragma("unroll")                                                           \
    for (int nf = 0; nf < 4; ++nf) {                                            \
        acc[2*(q)][nf]   = MFMA(afr[0], bfr[nf][0], acc[2*(q)][nf]);            \
        acc[2*(q)][nf]   = MFMA(afr[1], bfr[nf][1], acc[2*(q)][nf]);            \
        acc[2*(q)+1][nf] = MFMA(afr[2], bfr[nf][0], acc[2*(q)+1][nf]);          \
        acc[2*(q)+1][nf] = MFMA(afr[3], bfr[nf][1], acc[2*(q)+1][nf]);          \
    } } while (0)

// regular phase: stage, ONE barrier, lgkm, shadow{next-A preload + MFMA}
#define PHASE(q, bfr, afrC, dn, qn, afrN, STAGE_EXPR) do {                      \
    STAGE_EXPR;                                                                 \
    __builtin_amdgcn_s_barrier();                                               \
    asm volatile("s_waitcnt lgkmcnt(0)" ::: "memory");                          \
    __builtin_amdgcn_s_setprio(1);                                              \
    LDA4(dn, qn, afrN);                                                         \
    MFMA16(q, bfr, afrC);                                                       \
    __builtin_amdgcn_s_setprio(0);                                              \
} while (0)

// checkpoint phase (P4/P8): + VM4 pre-barrier, + next-B preload in shadow
#define PHASEX(q, bfr, afrC, dn, qn, afrN, bnxt, dnb, STAGE_EXPR) do {          \
    STAGE_EXPR;                                                                 \
    VM4;                                                                        \
    __builtin_amdgcn_s_barrier();                                               \
    asm volatile("s_waitcnt lgkmcnt(0)" ::: "memory");                          \
    __builtin_amdgcn_s_setprio(1);                                              \
    LDB_ALL(dnb, bnxt);                                                         \
    LDA4(dn, qn, afrN);                                                         \
    MFMA16(q, bfr, afrC);                                                       \
    __builtin_amdgcn_s_setprio(0);                                              \
} while (0)

__global__ __launch_bounds__(512, 2) void gemm_kernel(
    const unsigned short* __restrict__ A,
    const unsigned short* __restrict__ Bt,
    float* __restrict__ C)
{
    __shared__ __align__(16) unsigned short lds[65536];   // 128 KiB

    const int tid  = threadIdx.x;
    const int lane = tid & 63;
    const int wave = tid >> 6;
    const int wm = wave >> 2;          // 0..1
    const int wn = wave & 3;           // 0..3

    // XCD-aware swizzle: 512 blocks, 512 % 8 == 0 -> bijective
    const int bid = blockIdx.x;
    const int swz = (bid & 7) * 64 + (bid >> 3);
    const int tm = swz >> 4;           // 32 M-tiles
    const int tn = swz & 15;           // 16 N-tiles

    const int frow = lane & 15;
    const int kgrp = lane >> 4;
    const int xorv = (frow & 7) << 4;  // read-side byte XOR (bits 4-6)

    // staging: thread tid covers LDS bytes [tid*16, tid*16+16) (+8KB for h=1).
    // source col pre-swizzled with the same involution; LDS dest stays linear.
    const int st_row  = tid >> 3;                                            // 0..63
    const int st_colE = ((((tid & 7) * 16) ^ (((tid >> 3) & 7) << 4)) >> 1); // elems
    const unsigned short* aSrc = A  + (size_t)(tm * 256 + st_row) * KF + st_colE;
    const unsigned short* bSrc = Bt + (size_t)(tn * 256 + st_row) * KF + st_colE;
    const int dstE = tid * 8;

    f32x4 acc[8][4] = {};

    auto stage = [&](int isB, int d, int h, int kt) {
        const unsigned short* src =
            (isB ? bSrc : aSrc) + (size_t)((h) * 128) * KF + (kt) * 64;
        unsigned short* dst = (unsigned short*)&lds[isB * 32768 + (d * 2 + h) * 8192 + dstE];
        __builtin_amdgcn_global_load_lds(
            (const __attribute__((address_space(1))) void*)src,
            (__attribute__((address_space(3))) void*)dst, 16, 0, 0);
        __builtin_amdgcn_global_load_lds(
            (const __attribute__((address_space(1))) void*)(src + (size_t)64 * KF),
            (__attribute__((address_space(3))) void*)(dst + 4096), 16, 0, 0);
    };

    auto ldA = [&](int d, int mf, int kk) -> bf16x8 {
        int off = (d * 2 + wm) * 8192 + (mf * 16 + frow) * 64
                + ((((kk << 6) | (kgrp << 4)) ^ xorv) >> 1);
        return *(const bf16x8*)&lds[off];
    };
    auto ldB = [&](int d, int nf, int kk) -> bf16x8 {
        int off = 32768 + (d * 2 + (wn >> 1)) * 8192
                + ((wn & 1) * 64 + nf * 16 + frow) * 64
                + ((((kk << 6) | (kgrp << 4)) ^ xorv) >> 1);
        return *(const bf16x8*)&lds[off];
    };

    bf16x8 bfrP[4][2], bfrQ[4][2];
    bf16x8 afrP[4], afrQ[4];

    // ---- prologue: B-d0(K0), A-d0(K0), B-d1(K1); VM4 retires B-d0+A-d0
    // (FIFO), leaving B-d1 in flight = steady-state carry. After the barrier
    // all waves' K0 writes are visible -> preload bfrP + P1's A-frags.
    stage(1, 0, 0, 0); stage(1, 0, 1, 0);
    stage(0, 0, 0, 0); stage(0, 0, 1, 0);
    stage(1, 1, 0, 1); stage(1, 1, 1, 1);
    VM4;
    __builtin_amdgcn_s_barrier();
    asm volatile("" ::: "memory");     // keep preloads below the barrier
    LDB_ALL(0, bfrP);
    LDA4(0, 0, afrP);

    // ---- main loop: 64 K-tiles, 2 per iteration ----
    for (int i = 0; i < 32; ++i) {
        const int kt1 = 2 * i + 1;
        const int kt2 = (2 * i + 2) & 63;   // wrap on last iter (dead data, safe)
        const int kt3 = (2 * i + 3) & 63;

        PHASE (0, bfrP, afrP, 0, 1, afrQ, stage(0, 1, 0, kt1));           // P1
        PHASE (1, bfrP, afrQ, 0, 2, afrP, stage(0, 1, 1, kt1));           // P2
        PHASE (2, bfrP, afrP, 0, 3, afrQ, stage(1, 0, 0, kt2));           // P3
        PHASEX(3, bfrP, afrQ, 1, 0, afrP, bfrQ, 1, stage(1, 0, 1, kt2));  // P4
        PHASE (0, bfrQ, afrP, 1, 1, afrQ, stage(0, 0, 0, kt2));           // P5
        PHASE (1, bfrQ, afrQ, 1, 2, afrP, stage(0, 0, 1, kt2));           // P6
        PHASE (2, bfrQ, afrP, 1, 3, afrQ, stage(1, 1, 0, kt3));           // P7
        PHASEX(3, bfrQ, afrQ, 0, 0, afrP, bfrP, 0, stage(1, 1, 1, kt3));  // P8
    }

    asm volatile("s_waitcnt vmcnt(0)" ::: "memory");

    // ---- epilogue: C/D layout col=lane&15, row=(lane>>4)*4+reg ----
    const int rgrp = lane >> 4, coll = lane & 15;
    #pragma unroll
    for (int mf = 0; mf < 8; ++mf)
        #pragma unroll
        for (int nf = 0; nf < 4; ++nf) {
            size_t row0 = (size_t)(tm * 256 + wm * 128 + mf * 16 + rgrp * 4);
            size_t col  = (size_t)(tn * 256 + wn * 64 + nf * 16 + coll);
            #pragma unroll
            for (int r = 0; r < 4; ++r)
                C[(row0 + r) * NF + col] = acc[mf][nf][r];
        }
}

extern "C" void kernel_launch(void* const* d_in, const int* in_sizes, int n_in,
                              void* d_out, int out_size, void* d_ws, size_t ws_size,
                              hipStream_t stream) {
    const float* x  = (const float*)d_in[0];
    const float* W  = (const float*)d_in[1];
    const float* U  = (const float*)d_in[2];
    const float* s  = (const float*)d_in[3];
    const float* Vt = (const float*)d_in[4];
    float* out = (float*)d_out;

    unsigned short* Wt = (unsigned short*)d_ws;                  // 32 MB
    unsigned short* xb = Wt + (size_t)NF * KF;                   // 64 MB

    prep_w_kernel<<<dim3(KF / 64, NF / 64), 256, 0, stream>>>(W, U, s, Vt, Wt);
    prep_x_kernel<<<(TOKENS * KF / 8) / 256, 256, 0, stream>>>(x, xb);
    gemm_kernel<<<(TOKENS / 256) * (NF / 256), 512, 0, stream>>>(xb, Wt, out);
}